// Round 5
// baseline (11712.728 us; speedup 1.0000x reference)
//
#include <hip/hip_runtime.h>
#include <hip/hip_bf16.h>

// LSTM: B=64, D=32, H=512, T=1024. gates = [h,x] @ [W_hh;W_ih]^T + b_ih + b_hh
// Round 5: wave-decoupled dataflow. h in separate hi/lo bf16 planes moved by
// relaxed AGENT atomics (write-through / bypass, validated R4). Consumer loads
// land directly in MFMA fragment regs (2xu64 per chunk, zero unpack), pinned
// as one burst via sched_barrier -> single vmcnt cascade, not 16 round-trips.
// Per-WAVE flags (128/group/step); no __syncthreads in the loop; release =
// h stores -> s_waitcnt vmcnt(0) -> flag store. Projection via atomicAdd
// after the flag (off critical path) + k_reduce epilogue.
// 128 blocks (4 batch-groups x 32 slices of 16 units), 256 thr (4 waves).

typedef unsigned short ushort_t;
typedef unsigned int   uint_t;
typedef unsigned long long u64_t;
typedef __attribute__((ext_vector_type(8))) short bf16x8;
typedef __attribute__((ext_vector_type(4))) float f32x4;

#define T_STEPS 1024
#define HID     512
#define KDIM    544   // 512 h + 32 x
#define NBLK    128   // 4 groups * 32 slices
#define NTHR    256

__device__ inline ushort_t f2bf(float x) {
    __hip_bfloat16 h = __float2bfloat16(x);
    return *(ushort_t*)&h;
}
__device__ inline float bf2f(ushort_t u) {
    __hip_bfloat16 h = *(__hip_bfloat16*)&u;
    return __bfloat162float(h);
}

__device__ inline f32x4 MFMA(bf16x8 a, bf16x8 b, f32x4 c) {
    return __builtin_amdgcn_mfma_f32_16x16x32_bf16(a, b, c, 0, 0, 0);
}

// is_tanh: tanh(v)=(1-e)/(1+e), e=2^(-2.885*v); sigmoid(v)=1/(1+e), e=2^(-1.4427*v)
__device__ inline float act_gate(float v, int is_tanh) {
    float vc = fminf(fmaxf(v, -43.f), 43.f);
    float kk = is_tanh ? -2.88539008f : -1.44269504f;
    float e  = __builtin_exp2f(vc * kk);
    float num = is_tanh ? (1.f - e) : 1.f;
    return num * __builtin_amdgcn_rcpf(1.f + e);
}

__device__ inline float sel4(int i, float a, float b, float c, float d) {
    return (i == 0) ? a : (i == 1) ? b : (i == 2) ? c : d;
}

// ---------- prep kernels ----------

__global__ void k_init(uint_t* flags, uint_t* hhi32, uint_t* hlo32, f32x4* part4) {
    int i = blockIdx.x * 256 + threadIdx.x;     // grid 2048x256 = 524288
    flags[i] = 0;                                // 1024*4*128 u32 = exactly 524288
    part4[i] = (f32x4){0.f, 0.f, 0.f, 0.f};     // 524288*16B = 8.39 MB = whole part
    if (i < 32768) { hhi32[i] = 0; hlo32[i] = 0; }  // h ring, both slots, both planes
}

__global__ void k_wcat(const float* __restrict__ wih, const float* __restrict__ whh,
                       ushort_t* __restrict__ wh, ushort_t* __restrict__ wl) {
    int r = blockIdx.x;                          // 2048 gate rows
    for (int k = threadIdx.x; k < KDIM; k += 256) {
        float w = (k < 512) ? whh[r * 512 + k] : wih[r * 32 + (k - 512)];
        ushort_t hh = f2bf(w);
        ushort_t ll = f2bf(w - bf2f(hh));
        wh[r * KDIM + k] = hh;
        wl[r * KDIM + k] = ll;
    }
}

// input (B=64, D=32, T=1024) fp32 -> xbuf[t][b][d] bf16 hi/lo
__global__ void k_xbuf(const float* __restrict__ in,
                       ushort_t* __restrict__ xh, ushort_t* __restrict__ xl) {
    __shared__ float tile[64][65];
    int bp = blockIdx.x >> 4;                    // batch pair 0..31
    int tt = blockIdx.x & 15;                    // t tile 0..15
    int t0 = tt * 64;
    int wv = threadIdx.x >> 6, l = threadIdx.x & 63;
    for (int r = wv * 16; r < wv * 16 + 16; r++) {
        int b = bp * 2 + (r >> 5), d = r & 31;
        tile[r][l] = in[(b * 32 + d) * 1024 + t0 + l];
    }
    __syncthreads();
    for (int i = 0; i < 16; i++) {
        int tl = wv * 16 + i;
        float v = tile[l][tl];
        ushort_t hh = f2bf(v);
        ushort_t ll = f2bf(v - bf2f(hh));
        int o = (t0 + tl) * 2048 + bp * 64 + l;  // = t*64*32 + b*32 + d
        xh[o] = hh;
        xl[o] = ll;
    }
}

// final: out[b][t] = conv_b + sum_s part[b][t][s]
__global__ void k_reduce(const float* __restrict__ part, float* __restrict__ out,
                         const float* __restrict__ cvb) {
    int idx = blockIdx.x * 256 + threadIdx.x;    // 65536 = (b,t) pairs
    const float* p = part + (size_t)idx * 32;
    float s = 0.f;
    #pragma unroll
    for (int k = 0; k < 8; k++) {
        f32x4 v = *(const f32x4*)(p + k * 4);
        s += (v[0] + v[1]) + (v[2] + v[3]);
    }
    out[idx] = s + cvb[0];
}

// ---------- main recurrent kernel ----------

__global__ __launch_bounds__(NTHR, 1) void k_lstm(
    const ushort_t* __restrict__ wh, const ushort_t* __restrict__ wlo,
    const ushort_t* __restrict__ xh, const ushort_t* __restrict__ xl,
    ushort_t* hhi, ushort_t* hlo, uint_t* flags,
    const float* __restrict__ bih, const float* __restrict__ bhh,
    const float* __restrict__ convw, float* __restrict__ part)
{
    const int tid = threadIdx.x;
    const int w   = tid >> 6;          // wave 0..3 (unit nibble)
    const int l   = tid & 63;
    const int g   = blockIdx.x >> 5;   // batch group 0..3
    const int s   = blockIdx.x & 31;   // hidden slice 0..31 (16 units each)
    const int n   = l & 15;            // B-tile row within wave
    const int q   = l >> 4;            // quad
    const int gtn = n >> 2;            // gate 0..3 (i,f,g,o)
    const int u   = n & 3;             // unit within wave
    const int j   = s * 16 + w * 4 + u;// hidden unit 0..511
    const int row = gtn * HID + j;     // gate row 0..2047
    const int b0  = g * 16;

    __shared__ ushort_t blo[64][552];  // W_lo slice, padded stride

    // stage W_lo to LDS: 64 rows x 544, 8-elem (16B) chunks
    for (int e = tid; e < 64 * 68; e += NTHR) {
        int rl = e / 68, ch = e - rl * 68;
        int ww = rl >> 4, nn = rl & 15;
        int gg = nn >> 2, uu = nn & 3;
        int rr = gg * HID + s * 16 + ww * 4 + uu;
        *(bf16x8*)&blo[rl][ch * 8] = *(const bf16x8*)(wlo + rr * KDIM + ch * 8);
    }

    // W_hi fragments in registers: 17 K-chunks
    bf16x8 Bh[17];
    #pragma unroll
    for (int c = 0; c < 17; c++)
        Bh[c] = *(const bf16x8*)(wh + row * KDIM + c * 32 + q * 8);

    const float bias = bih[row] + bhh[row];
    const float cw   = convw[j];
    float cst[4] = {0.f, 0.f, 0.f, 0.f};

    __syncthreads();
    const int rl16 = w * 16 + n;

    union frag { u64_t d[2]; bf16x8 v; };

    for (int t = 0; t < T_STEPS; t++) {
        frag Ah[17], Al[17];
        // x fragment: no dependence on flags -> prefetch into regs before poll
        {
            int xo = (t * 64 + b0 + n) * 32 + q * 8;
            Ah[16].v = *(const bf16x8*)(xh + xo);
            Al[16].v = *(const bf16x8*)(xl + xo);
        }

        // every wave polls the 128 per-wave flags of its group (2 per lane)
        if (t > 0) {
            const u64_t* fb = (const u64_t*)(flags + ((t - 1) * 4 + g) * 128);
            for (;;) {
                u64_t f = __hip_atomic_load(fb + l, __ATOMIC_RELAXED,
                                            __HIP_MEMORY_SCOPE_AGENT);
                if (__all(((uint_t)f != 0) && ((uint_t)(f >> 32) != 0))) break;
            }
        }

        // h fragments: direct atomic u64 loads into fragment registers,
        // pinned as one burst (single vmcnt cascade, no unpack).
        {
            const u64_t* ph = (const u64_t*)hhi +
                              (size_t)((((t & 1) * 4 + g) * 16 + n)) * 128;
            const u64_t* pl = (const u64_t*)hlo +
                              (size_t)((((t & 1) * 4 + g) * 16 + n)) * 128;
            #pragma unroll
            for (int c = 0; c < 16; c++) {
                int o = c * 8 + q * 2;
                Ah[c].d[0] = __hip_atomic_load(ph + o,     __ATOMIC_RELAXED,
                                               __HIP_MEMORY_SCOPE_AGENT);
                Ah[c].d[1] = __hip_atomic_load(ph + o + 1, __ATOMIC_RELAXED,
                                               __HIP_MEMORY_SCOPE_AGENT);
                Al[c].d[0] = __hip_atomic_load(pl + o,     __ATOMIC_RELAXED,
                                               __HIP_MEMORY_SCOPE_AGENT);
                Al[c].d[1] = __hip_atomic_load(pl + o + 1, __ATOMIC_RELAXED,
                                               __HIP_MEMORY_SCOPE_AGENT);
            }
        }
        __builtin_amdgcn_sched_barrier(0);  // all loads issued before MFMA loop

        f32x4 a0 = {0,0,0,0}, a1 = {0,0,0,0}, a2 = {0,0,0,0},
              a3 = {0,0,0,0}, a4 = {0,0,0,0}, a5 = {0,0,0,0};
        #pragma unroll
        for (int c = 0; c < 17; c++) {
            bf16x8 bl_ = *(const bf16x8*)&blo[rl16][c * 32 + q * 8];
            if (c & 1) {
                a1 = MFMA(Ah[c].v, Bh[c], a1);
                a3 = MFMA(Ah[c].v, bl_,   a3);
                a5 = MFMA(Al[c].v, Bh[c], a5);
            } else {
                a0 = MFMA(Ah[c].v, Bh[c], a0);
                a2 = MFMA(Ah[c].v, bl_,   a2);
                a4 = MFMA(Al[c].v, Bh[c], a4);
            }
        }
        f32x4 D = (a0 + a1) + (a2 + a3) + (a4 + a5);

        // epilogue: lane holds gate row n for batches m=q*4+r
        float pr[4];
        uint_t hhv[4], llv[4];
        #pragma unroll
        for (int r = 0; r < 4; r++) {
            float v   = D[r] + bias;
            float act = act_gate(v, gtn == 2);
            float v4  = __shfl_xor(act, 4);
            float v8  = __shfl_xor(act, 8);
            float v12 = __shfl_xor(v4, 8);
            // gate G lives at arr[gtn ^ G]; arr = {act, v4, v8, v12}
            float iv = sel4(gtn,     act, v4, v8, v12);
            float fv = sel4(gtn ^ 1, act, v4, v8, v12);
            float gv = sel4(gtn ^ 2, act, v4, v8, v12);
            float ov = sel4(gtn ^ 3, act, v4, v8, v12);
            float cc = fv * cst[r] + iv * gv;
            cst[r] = cc;
            float th = act_gate(cc, 1);
            float h  = ov * th;
            ushort_t hb = f2bf(h);
            hhv[r] = (uint_t)hb;
            llv[r] = (uint_t)f2bf(h - bf2f(hb));
            pr[r]  = cw * h;
        }

        // pack unit pairs (u even gets u+1's halves) and store h_t to ring
        // slot (t+1)&1 via write-through atomics. ushort idx m2*512+j ->
        // dword idx m2*256 + (j>>1).
        {
            uint_t* dh = (uint_t*)hhi + (size_t)(((t + 1) & 1) * 4 + g) * 4096;
            uint_t* dl = (uint_t*)hlo + (size_t)(((t + 1) & 1) * 4 + g) * 4096;
            #pragma unroll
            for (int r = 0; r < 4; r++) {
                uint_t hp_ = (uint_t)__shfl_xor((int)hhv[r], 1);
                uint_t lp_ = (uint_t)__shfl_xor((int)llv[r], 1);
                if (gtn == 0 && !(u & 1)) {
                    int di = (q * 4 + r) * 256 + (j >> 1);
                    __hip_atomic_store(dh + di, hhv[r] | (hp_ << 16),
                                       __ATOMIC_RELAXED, __HIP_MEMORY_SCOPE_AGENT);
                    __hip_atomic_store(dl + di, llv[r] | (lp_ << 16),
                                       __ATOMIC_RELAXED, __HIP_MEMORY_SCOPE_AGENT);
                }
            }
        }
        // release: write-through stores complete at L3, then per-wave flag
        __builtin_amdgcn_s_waitcnt(0x0F70);   // vmcnt(0), ignore exp/lgkm
        if (l == 0)
            __hip_atomic_store(flags + (t * 4 + g) * 128 + s * 4 + w, 1u,
                               __ATOMIC_RELAXED, __HIP_MEMORY_SCOPE_AGENT);

        // projection partial (off critical path, after flag): sum over this
        // wave's 4 units (lane bits 0..1), one atomicAdd per batch from n==0
        #pragma unroll
        for (int r = 0; r < 4; r++) {
            pr[r] += __shfl_xor(pr[r], 1);
            pr[r] += __shfl_xor(pr[r], 2);
        }
        if (n == 0) {
            #pragma unroll
            for (int r = 0; r < 4; r++)
                atomicAdd(part + (size_t)((b0 + q * 4 + r) * 1024 + t) * 32 + s,
                          pr[r]);
        }
    }
}

extern "C" void kernel_launch(void* const* d_in, const int* in_sizes, int n_in,
                              void* d_out, int out_size, void* d_ws, size_t ws_size,
                              hipStream_t stream) {
    const float* in  = (const float*)d_in[0];
    const float* Wih = (const float*)d_in[1];
    const float* Whh = (const float*)d_in[2];
    const float* bih = (const float*)d_in[3];
    const float* bhh = (const float*)d_in[4];
    const float* cvw = (const float*)d_in[5];
    const float* cvb = (const float*)d_in[6];
    float* out = (float*)d_out;

    char* ws = (char*)d_ws;
    ushort_t* wh  = (ushort_t*)ws; ws += (size_t)2048 * KDIM * 2;      // 2,228,224
    ushort_t* wl  = (ushort_t*)ws; ws += (size_t)2048 * KDIM * 2;
    ushort_t* xh  = (ushort_t*)ws; ws += (size_t)1024 * 64 * 32 * 2;   // 4,194,304
    ushort_t* xl  = (ushort_t*)ws; ws += (size_t)1024 * 64 * 32 * 2;
    ushort_t* hhi = (ushort_t*)ws; ws += (size_t)2 * 64 * HID * 2;     // 131,072
    ushort_t* hlo = (ushort_t*)ws; ws += (size_t)2 * 64 * HID * 2;
    uint_t*   fl  = (uint_t*)ws;   ws += (size_t)T_STEPS * 4 * 128 * 4;// 2,097,152
    float*    pp  = (float*)ws;    ws += (size_t)64 * 1024 * 32 * 4;   // 8,388,608
    // total ~23.6 MB of ws

    k_init<<<2048, 256, 0, stream>>>(fl, (uint_t*)hhi, (uint_t*)hlo, (f32x4*)pp);
    k_wcat<<<2048, 256, 0, stream>>>(Wih, Whh, wh, wl);
    k_xbuf<<<512, 256, 0, stream>>>(in, xh, xl);
    k_lstm<<<NBLK, NTHR, 0, stream>>>(wh, wl, xh, xl, hhi, hlo, fl,
                                      bih, bhh, cvw, pp);
    k_reduce<<<256, 256, 0, stream>>>(pp, out, cvb);
}

// Round 6
// 5260.803 us; speedup vs baseline: 2.2264x; 2.2264x over previous
//
#include <hip/hip_runtime.h>
#include <hip/hip_bf16.h>

// LSTM: B=64, D=32, H=512, T=1024. gates = [h,x] @ [W_hh;W_ih]^T + b_ih + b_hh
// Round 6: contention-free L3 dataflow.
//  - flags: one 128B line per producing block, value-coded (==t), ring-4.
//  - h ring: one 128B line per producing WAVE per plane: h64[slot][g][wg][m],
//    wg = slice*4+wave owns units wg*4..wg*4+3, m = 16 batches -> 16 u64/line.
//    Producer: pack 4 units' bf16 into u64 (2 shuffles), 8 u64 stores/wave.
//    Consumer: fragment chunk = 2 u64 relaxed-agent bypass loads, no unpack.
//  - projection partials via LDS predsh + 16 NT stores (no atomics).
// 128 blocks (4 batch-groups x 32 slices of 16 units), 256 thr (4 waves).
// W_hi in VGPRs, W_lo in LDS. Relaxed agent atomics (write-through/bypass,
// validated R4/R5); release = stores -> vmcnt(0) -> barrier -> flag.

typedef unsigned short ushort_t;
typedef unsigned int   uint_t;
typedef unsigned long long u64_t;
typedef __attribute__((ext_vector_type(8))) short bf16x8;
typedef __attribute__((ext_vector_type(4))) float f32x4;

#define T_STEPS 1024
#define HID     512
#define KDIM    544   // 512 h + 32 x
#define NBLK    128   // 4 groups * 32 slices
#define NTHR    256

__device__ inline ushort_t f2bf(float x) {
    __hip_bfloat16 h = __float2bfloat16(x);
    return *(ushort_t*)&h;
}
__device__ inline float bf2f(ushort_t u) {
    __hip_bfloat16 h = *(__hip_bfloat16*)&u;
    return __bfloat162float(h);
}

__device__ inline f32x4 MFMA(bf16x8 a, bf16x8 b, f32x4 c) {
    return __builtin_amdgcn_mfma_f32_16x16x32_bf16(a, b, c, 0, 0, 0);
}

// is_tanh: tanh(v)=(1-e)/(1+e), e=2^(-2.885*v); sigmoid(v)=1/(1+e), e=2^(-1.4427*v)
__device__ inline float act_gate(float v, int is_tanh) {
    float vc = fminf(fmaxf(v, -43.f), 43.f);
    float kk = is_tanh ? -2.88539008f : -1.44269504f;
    float e  = __builtin_exp2f(vc * kk);
    float num = is_tanh ? (1.f - e) : 1.f;
    return num * __builtin_amdgcn_rcpf(1.f + e);
}

__device__ inline float sel4(int i, float a, float b, float c, float d) {
    return (i == 0) ? a : (i == 1) ? b : (i == 2) ? c : d;
}

// ---------- prep kernels ----------

__global__ void k_init(uint_t* flags, uint_t* hhi32, uint_t* hlo32) {
    int i = blockIdx.x * 256 + threadIdx.x;      // grid 128x256 = 32768
    if (i < 16384) flags[i] = 0;                 // 4 rings*4 g*32 s*32 pad u32
    hhi32[i] = 0;                                // 2 slots*4g*128wg*16m u64 = 32768 u32
    hlo32[i] = 0;
}

__global__ void k_wcat(const float* __restrict__ wih, const float* __restrict__ whh,
                       ushort_t* __restrict__ wh, ushort_t* __restrict__ wl) {
    int r = blockIdx.x;                          // 2048 gate rows
    for (int k = threadIdx.x; k < KDIM; k += 256) {
        float w = (k < 512) ? whh[r * 512 + k] : wih[r * 32 + (k - 512)];
        ushort_t hh = f2bf(w);
        ushort_t ll = f2bf(w - bf2f(hh));
        wh[r * KDIM + k] = hh;
        wl[r * KDIM + k] = ll;
    }
}

// input (B=64, D=32, T=1024) fp32 -> xbuf[t][b][d] bf16 hi/lo
__global__ void k_xbuf(const float* __restrict__ in,
                       ushort_t* __restrict__ xh, ushort_t* __restrict__ xl) {
    __shared__ float tile[64][65];
    int bp = blockIdx.x >> 4;                    // batch pair 0..31
    int tt = blockIdx.x & 15;                    // t tile 0..15
    int t0 = tt * 64;
    int wv = threadIdx.x >> 6, l = threadIdx.x & 63;
    for (int r = wv * 16; r < wv * 16 + 16; r++) {
        int b = bp * 2 + (r >> 5), d = r & 31;
        tile[r][l] = in[(b * 32 + d) * 1024 + t0 + l];
    }
    __syncthreads();
    for (int i = 0; i < 16; i++) {
        int tl = wv * 16 + i;
        float v = tile[l][tl];
        ushort_t hh = f2bf(v);
        ushort_t ll = f2bf(v - bf2f(hh));
        int o = (t0 + tl) * 2048 + bp * 64 + l;  // = t*64*32 + b*32 + d
        xh[o] = hh;
        xl[o] = ll;
    }
}

// final: out[b][t] = conv_b + sum_s part[b][t][s]
__global__ void k_reduce(const float* __restrict__ part, float* __restrict__ out,
                         const float* __restrict__ cvb) {
    int idx = blockIdx.x * 256 + threadIdx.x;    // 65536 = (b,t) pairs
    const float* p = part + (size_t)idx * 32;
    float s = 0.f;
    #pragma unroll
    for (int k = 0; k < 8; k++) {
        f32x4 v = *(const f32x4*)(p + k * 4);
        s += (v[0] + v[1]) + (v[2] + v[3]);
    }
    out[idx] = s + cvb[0];
}

// ---------- main recurrent kernel ----------

__global__ __launch_bounds__(NTHR, 1) void k_lstm(
    const ushort_t* __restrict__ wh, const ushort_t* __restrict__ wlo,
    const ushort_t* __restrict__ xh, const ushort_t* __restrict__ xl,
    u64_t* h64hi, u64_t* h64lo, uint_t* flags,
    const float* __restrict__ bih, const float* __restrict__ bhh,
    const float* __restrict__ convw, float* __restrict__ part)
{
    const int tid = threadIdx.x;
    const int w   = tid >> 6;          // wave 0..3 (unit nibble)
    const int l   = tid & 63;
    const int g   = blockIdx.x >> 5;   // batch group 0..3
    const int s   = blockIdx.x & 31;   // hidden slice 0..31 (16 units each)
    const int n   = l & 15;            // B-tile row within wave
    const int q   = l >> 4;            // quad
    const int gtn = n >> 2;            // gate 0..3 (i,f,g,o)
    const int u   = n & 3;             // unit within wave
    const int j   = s * 16 + w * 4 + u;// hidden unit 0..511
    const int row = gtn * HID + j;     // gate row 0..2047
    const int b0  = g * 16;
    const int wg  = s * 4 + w;         // producing-wave id in group, 0..127

    __shared__ ushort_t blo[64][552];  // W_lo slice, padded stride
    __shared__ float predsh[4][16];

    // stage W_lo to LDS: 64 rows x 544, 8-elem (16B) chunks
    for (int e = tid; e < 64 * 68; e += NTHR) {
        int rl = e / 68, ch = e - rl * 68;
        int ww = rl >> 4, nn = rl & 15;
        int gg = nn >> 2, uu = nn & 3;
        int rr = gg * HID + s * 16 + ww * 4 + uu;
        *(bf16x8*)&blo[rl][ch * 8] = *(const bf16x8*)(wlo + rr * KDIM + ch * 8);
    }

    // W_hi fragments in registers: 17 K-chunks
    bf16x8 Bh[17];
    #pragma unroll
    for (int c = 0; c < 17; c++)
        Bh[c] = *(const bf16x8*)(wh + row * KDIM + c * 32 + q * 8);

    const float bias = bih[row] + bhh[row];
    const float cw   = convw[j];
    float cst[4] = {0.f, 0.f, 0.f, 0.f};

    __syncthreads();
    const int rl16 = w * 16 + n;

    union frag { u64_t d[2]; bf16x8 v; };

    for (int t = 0; t < T_STEPS; t++) {
        frag Ah[17], Al[17];
        // x fragment: no dependence on flags -> prefetch into regs before poll
        {
            int xo = (t * 64 + b0 + n) * 32 + q * 8;
            Ah[16].v = *(const bf16x8*)(xh + xo);
            Al[16].v = *(const bf16x8*)(xl + xo);
        }

        if (t > 0) {
            if (w == 0) {
                // lane i polls slice i's private flag line; value == t
                const uint_t* my = flags +
                    (size_t)((((t - 1) & 3) * 4 + g) * 32 + (l & 31)) * 32;
                for (;;) {
                    uint_t f = __hip_atomic_load(my, __ATOMIC_RELAXED,
                                                 __HIP_MEMORY_SCOPE_AGENT);
                    if (__all(l >= 32 || f == (uint_t)t)) break;
                }
            }
            __syncthreads();
        }

        // h fragments: relaxed-agent u64 bypass loads straight into fragment
        // registers. h64[slot][g][wgp][m]: chunk c quad q row n ->
        // wgp = c*8+q*2 (units c*32+q*8..+3) and wgp+1 (next 4 units).
        {
            const u64_t* bp_ = h64hi + (size_t)(((t & 1) * 4 + g) * 128) * 16;
            const u64_t* bl_ = h64lo + (size_t)(((t & 1) * 4 + g) * 128) * 16;
            #pragma unroll
            for (int c = 0; c < 16; c++) {
                int o = (c * 8 + q * 2) * 16 + n;
                Ah[c].d[0] = __hip_atomic_load(bp_ + o,      __ATOMIC_RELAXED,
                                               __HIP_MEMORY_SCOPE_AGENT);
                Ah[c].d[1] = __hip_atomic_load(bp_ + o + 16, __ATOMIC_RELAXED,
                                               __HIP_MEMORY_SCOPE_AGENT);
                Al[c].d[0] = __hip_atomic_load(bl_ + o,      __ATOMIC_RELAXED,
                                               __HIP_MEMORY_SCOPE_AGENT);
                Al[c].d[1] = __hip_atomic_load(bl_ + o + 16, __ATOMIC_RELAXED,
                                               __HIP_MEMORY_SCOPE_AGENT);
            }
        }

        f32x4 a0 = {0,0,0,0}, a1 = {0,0,0,0}, a2 = {0,0,0,0},
              a3 = {0,0,0,0}, a4 = {0,0,0,0}, a5 = {0,0,0,0};
        #pragma unroll
        for (int c = 0; c < 17; c++) {
            bf16x8 bl_ = *(const bf16x8*)&blo[rl16][c * 32 + q * 8];
            if (c & 1) {
                a1 = MFMA(Ah[c].v, Bh[c], a1);
                a3 = MFMA(Ah[c].v, bl_,   a3);
                a5 = MFMA(Al[c].v, Bh[c], a5);
            } else {
                a0 = MFMA(Ah[c].v, Bh[c], a0);
                a2 = MFMA(Ah[c].v, bl_,   a2);
                a4 = MFMA(Al[c].v, Bh[c], a4);
            }
        }
        f32x4 D = (a0 + a1) + (a2 + a3) + (a4 + a5);

        // epilogue: lane holds gate row n for batches m=q*4+r
        float pr[4];
        uint_t hhv[4], llv[4];
        #pragma unroll
        for (int r = 0; r < 4; r++) {
            float v   = D[r] + bias;
            float act = act_gate(v, gtn == 2);
            float v4  = __shfl_xor(act, 4);
            float v8  = __shfl_xor(act, 8);
            float v12 = __shfl_xor(v4, 8);
            // gate G lives at arr[gtn ^ G]; arr = {act, v4, v8, v12}
            float iv = sel4(gtn,     act, v4, v8, v12);
            float fv = sel4(gtn ^ 1, act, v4, v8, v12);
            float gv = sel4(gtn ^ 2, act, v4, v8, v12);
            float ov = sel4(gtn ^ 3, act, v4, v8, v12);
            float cc = fv * cst[r] + iv * gv;
            cst[r] = cc;
            float th = act_gate(cc, 1);
            float h  = ov * th;
            ushort_t hb = f2bf(h);
            hhv[r] = (uint_t)hb;
            llv[r] = (uint_t)f2bf(h - bf2f(hb));
            pr[r]  = cw * h;
        }

        // projection partial: sum this wave's 4 units (lane bits 0..1)
        #pragma unroll
        for (int r = 0; r < 4; r++) {
            pr[r] += __shfl_xor(pr[r], 1);
            pr[r] += __shfl_xor(pr[r], 2);
        }
        if (n == 0) {
            #pragma unroll
            for (int r = 0; r < 4; r++) predsh[w][q * 4 + r] = pr[r];
        }

        // pack this wave's 4 units into u64 and store h_t to its OWN line
        // in ring slot (t+1)&1: h64[slot][g][wg][m2], lanes n==0, q=0..3.
        {
            u64_t* dh = h64hi + (size_t)((((t + 1) & 1) * 4 + g) * 128 + wg) * 16;
            u64_t* dl = h64lo + (size_t)((((t + 1) & 1) * 4 + g) * 128 + wg) * 16;
            #pragma unroll
            for (int r = 0; r < 4; r++) {
                uint_t h1 = (uint_t)__shfl_xor((int)hhv[r], 1);
                uint_t l1 = (uint_t)__shfl_xor((int)llv[r], 1);
                uint_t hp = hhv[r] | (h1 << 16);          // [u, u^1] on even u
                uint_t lp = llv[r] | (l1 << 16);
                uint_t h2 = (uint_t)__shfl_xor((int)hp, 2);
                uint_t l2 = (uint_t)__shfl_xor((int)lp, 2);
                if (n == 0) {
                    int m2 = q * 4 + r;
                    __hip_atomic_store(dh + m2,
                        (u64_t)hp | ((u64_t)h2 << 32),
                        __ATOMIC_RELAXED, __HIP_MEMORY_SCOPE_AGENT);
                    __hip_atomic_store(dl + m2,
                        (u64_t)lp | ((u64_t)l2 << 32),
                        __ATOMIC_RELAXED, __HIP_MEMORY_SCOPE_AGENT);
                }
            }
        }

        // release: write-through stores at L3, then block flag (own line)
        __builtin_amdgcn_s_waitcnt(0x0F70);   // vmcnt(0)
        __syncthreads();                      // all 4 waves' stores complete
        if (tid == 0)
            __hip_atomic_store(flags + (size_t)(((t & 3) * 4 + g) * 32 + s) * 32,
                               (uint_t)(t + 1),
                               __ATOMIC_RELAXED, __HIP_MEMORY_SCOPE_AGENT);
        if (tid < 16) {   // projection partials -> global (off critical path)
            float tot = (predsh[0][tid] + predsh[1][tid]) +
                        (predsh[2][tid] + predsh[3][tid]);
            __builtin_nontemporal_store(tot,
                part + (size_t)((b0 + tid) * 1024 + t) * 32 + s);
        }
        // next iteration's predsh writes are gated by its poll+barrier,
        // ordering them after this iteration's predsh reads.
    }
}

extern "C" void kernel_launch(void* const* d_in, const int* in_sizes, int n_in,
                              void* d_out, int out_size, void* d_ws, size_t ws_size,
                              hipStream_t stream) {
    const float* in  = (const float*)d_in[0];
    const float* Wih = (const float*)d_in[1];
    const float* Whh = (const float*)d_in[2];
    const float* bih = (const float*)d_in[3];
    const float* bhh = (const float*)d_in[4];
    const float* cvw = (const float*)d_in[5];
    const float* cvb = (const float*)d_in[6];
    float* out = (float*)d_out;

    char* ws = (char*)d_ws;
    ushort_t* wh  = (ushort_t*)ws; ws += (size_t)2048 * KDIM * 2;      // 2,228,224
    ushort_t* wl  = (ushort_t*)ws; ws += (size_t)2048 * KDIM * 2;
    ushort_t* xh  = (ushort_t*)ws; ws += (size_t)1024 * 64 * 32 * 2;   // 4,194,304
    ushort_t* xl  = (ushort_t*)ws; ws += (size_t)1024 * 64 * 32 * 2;
    u64_t*    hhi = (u64_t*)ws;    ws += (size_t)2 * 4 * 128 * 16 * 8; // 131,072
    u64_t*    hlo = (u64_t*)ws;    ws += (size_t)2 * 4 * 128 * 16 * 8;
    uint_t*   fl  = (uint_t*)ws;   ws += (size_t)4 * 4 * 32 * 32 * 4;  // 65,536
    float*    pp  = (float*)ws;    ws += (size_t)64 * 1024 * 32 * 4;   // 8,388,608
    // total ~21.6 MB of ws

    k_init<<<128, 256, 0, stream>>>(fl, (uint_t*)hhi, (uint_t*)hlo);
    k_wcat<<<2048, 256, 0, stream>>>(Wih, Whh, wh, wl);
    k_xbuf<<<512, 256, 0, stream>>>(in, xh, xl);
    k_lstm<<<NBLK, NTHR, 0, stream>>>(wh, wl, xh, xl, hhi, hlo, fl,
                                      bih, bhh, cvw, pp);
    k_reduce<<<256, 256, 0, stream>>>(pp, out, cvb);
}